// Round 1
// baseline (644.661 us; speedup 1.0000x reference)
//
#include <hip/hip_runtime.h>
#include <hip/hip_bf16.h>

#define EMBED 1024
#define HEADS 16
#define HDIM 64
#define NB 4
#define SEQ 2048

typedef __bf16 bf16_t;
typedef bf16_t bf16x8 __attribute__((ext_vector_type(8)));
typedef float f32x4 __attribute__((ext_vector_type(4)));

static __device__ __forceinline__ bf16x8 load_cvt8(const float* __restrict__ p) {
    f32x4 a = *reinterpret_cast<const f32x4*>(p);
    f32x4 b = *reinterpret_cast<const f32x4*>(p + 4);
    bf16x8 r;
    r[0] = (bf16_t)a[0]; r[1] = (bf16_t)a[1]; r[2] = (bf16_t)a[2]; r[3] = (bf16_t)a[3];
    r[4] = (bf16_t)b[0]; r[5] = (bf16_t)b[1]; r[6] = (bf16_t)b[2]; r[7] = (bf16_t)b[3];
    return r;
}

// ---------------- Projection: Y[n,h,s,:] = X[n,s,h*64:+64] @ W^T  (bf16 out) ----------
__global__ __launch_bounds__(256) void proj_kernel(const float* __restrict__ X,
                                                   const float* __restrict__ W,
                                                   bf16_t* __restrict__ Y) {
    const int lane = threadIdx.x & 63;
    const int wv = threadIdx.x >> 6;
    const int lr = lane & 15;   // A-row / C-col within tile
    const int lk = lane >> 4;   // k-group
    const int r0 = blockIdx.x * 64 + wv * 16;  // linear row = (n*SEQ+s)*HEADS + h

    const float* xrow = X + (size_t)(r0 + lr) * HDIM;
    bf16x8 a0 = load_cvt8(xrow + lk * 8);
    bf16x8 a1 = load_cvt8(xrow + 32 + lk * 8);

    f32x4 acc[4] = {};
#pragma unroll
    for (int t = 0; t < 4; ++t) {
        const float* wrow = W + (size_t)(t * 16 + lr) * HDIM;  // W[e][:]
        bf16x8 b0 = load_cvt8(wrow + lk * 8);
        bf16x8 b1 = load_cvt8(wrow + 32 + lk * 8);
        acc[t] = __builtin_amdgcn_mfma_f32_16x16x32_bf16(a0, b0, acc[t], 0, 0, 0);
        acc[t] = __builtin_amdgcn_mfma_f32_16x16x32_bf16(a1, b1, acc[t], 0, 0, 0);
    }
#pragma unroll
    for (int r = 0; r < 4; ++r) {
        int row = r0 + lk * 4 + r;
        int n = row / (SEQ * HEADS);
        int rem = row % (SEQ * HEADS);
        int s = rem / HEADS;
        int h = rem % HEADS;
        bf16_t* yrow = Y + ((size_t)(n * HEADS + h) * SEQ + s) * HDIM;
#pragma unroll
        for (int t = 0; t < 4; ++t)
            yrow[t * 16 + lr] = (bf16_t)acc[t][r];
    }
}

// ---------------- Flash attention per (n,h,q-tile) ----------------
#define QT 64
#define KT 64

__global__ __launch_bounds__(256) void attn_kernel(const bf16_t* __restrict__ Qp,
                                                   const bf16_t* __restrict__ Kp,
                                                   const bf16_t* __restrict__ Vp,
                                                   const int* __restrict__ mask,
                                                   bf16_t* __restrict__ AO) {
    __shared__ bf16_t Kt[64 * 64];    // [key][d], chunk-swizzled
    __shared__ bf16_t VtT[64 * 64];   // [d][key], chunk-swizzled (transposed V)
    __shared__ bf16_t Pw[4][16 * 64]; // per-wave P tile

    const int tid = threadIdx.x;
    const int lane = tid & 63;
    const int wv = tid >> 6;
    const int lr = lane & 15, lk = lane >> 4;

    const int nqt = SEQ / QT;           // 32
    const int nh = blockIdx.x / nqt;    // 0..63
    const int qt = blockIdx.x % nqt;
    const int n = nh / HEADS, h = nh % HEADS;

    const bf16_t* Qh = Qp + (size_t)nh * SEQ * HDIM;
    const bf16_t* Kh = Kp + (size_t)nh * SEQ * HDIM;
    const bf16_t* Vh = Vp + (size_t)nh * SEQ * HDIM;
    const int* mrow = mask + n * SEQ;

    const int q0 = qt * QT + wv * 16;
    bf16x8 aq0 = *(const bf16x8*)(Qh + (size_t)(q0 + lr) * HDIM + lk * 8);
    bf16x8 aq1 = *(const bf16x8*)(Qh + (size_t)(q0 + lr) * HDIM + 32 + lk * 8);

    float m[4], l[4];
    f32x4 accO[4] = {};
#pragma unroll
    for (int r = 0; r < 4; ++r) { m[r] = -1e30f; l[r] = 0.f; }
    const float scale = 0.03125f;  // 1/sqrt(1024)

    for (int kt = 0; kt < SEQ / KT; ++kt) {
        __syncthreads();
        {   // stage K: [key][d] with chunk-swizzle; coalesced global reads
            const bf16_t* Ksrc = Kh + (size_t)kt * KT * HDIM;
#pragma unroll
            for (int p = 0; p < 2; ++p) {
                int cid = tid + p * 256;
                int row = cid >> 3, c = cid & 7;
                bf16x8 v = *(const bf16x8*)(Ksrc + row * HDIM + c * 8);
                *(bf16x8*)(Kt + row * 64 + ((c ^ (row & 7)) * 8)) = v;
            }
            // stage V transposed: thread owns key=tid&63, chunks c0, c0+4
            const bf16_t* Vsrc = Vh + (size_t)kt * KT * HDIM;
            int key = tid & 63;
#pragma unroll
            for (int p = 0; p < 2; ++p) {
                int c0 = (tid >> 6) + p * 4;
                bf16x8 v = *(const bf16x8*)(Vsrc + key * HDIM + c0 * 8);
#pragma unroll
                for (int j = 0; j < 8; ++j) {
                    int d = c0 * 8 + j;
                    VtT[d * 64 + (((key >> 3) ^ (d & 7)) << 3) + (key & 7)] = v[j];
                }
            }
        }
        __syncthreads();

        // QK^T for this wave's 16 q-rows x 64 keys
        f32x4 s[4];
#pragma unroll
        for (int ct = 0; ct < 4; ++ct) {
            int krow = ct * 16 + lr;
            bf16x8 bk0 = *(const bf16x8*)(Kt + krow * 64 + ((lk ^ (krow & 7)) * 8));
            bf16x8 bk1 = *(const bf16x8*)(Kt + krow * 64 + (((lk + 4) ^ (krow & 7)) * 8));
            f32x4 z = {};
            z = __builtin_amdgcn_mfma_f32_16x16x32_bf16(aq0, bk0, z, 0, 0, 0);
            z = __builtin_amdgcn_mfma_f32_16x16x32_bf16(aq1, bk1, z, 0, 0, 0);
            s[ct] = z;
        }
        // scale + mask
        int mv[4];
#pragma unroll
        for (int ct = 0; ct < 4; ++ct) mv[ct] = mrow[kt * KT + ct * 16 + lr];
#pragma unroll
        for (int ct = 0; ct < 4; ++ct) {
#pragma unroll
            for (int r = 0; r < 4; ++r)
                s[ct][r] = (mv[ct] == 0) ? -1e30f : s[ct][r] * scale;
        }
        // online softmax
        float fac[4];
#pragma unroll
        for (int r = 0; r < 4; ++r) {
            float v = fmaxf(fmaxf(s[0][r], s[1][r]), fmaxf(s[2][r], s[3][r]));
            v = fmaxf(v, __shfl_xor(v, 1));
            v = fmaxf(v, __shfl_xor(v, 2));
            v = fmaxf(v, __shfl_xor(v, 4));
            v = fmaxf(v, __shfl_xor(v, 8));
            float mn = fmaxf(m[r], v);
            fac[r] = __expf(m[r] - mn);
            m[r] = mn;
        }
        float rs[4] = {0.f, 0.f, 0.f, 0.f};
#pragma unroll
        for (int ct = 0; ct < 4; ++ct) {
#pragma unroll
            for (int r = 0; r < 4; ++r) {
                float p = __expf(s[ct][r] - m[r]);
                s[ct][r] = p;
                rs[r] += p;
            }
        }
#pragma unroll
        for (int r = 0; r < 4; ++r) {
            float v = rs[r];
            v += __shfl_xor(v, 1);
            v += __shfl_xor(v, 2);
            v += __shfl_xor(v, 4);
            v += __shfl_xor(v, 8);
            l[r] = l[r] * fac[r] + v;
#pragma unroll
            for (int t = 0; t < 4; ++t) accO[t][r] *= fac[r];
        }
        // P -> per-wave LDS (swizzled), then PV
        bf16_t* P = &Pw[wv][0];
#pragma unroll
        for (int ct = 0; ct < 4; ++ct) {
#pragma unroll
            for (int r = 0; r < 4; ++r) {
                int row = lk * 4 + r;
                int col = ct * 16 + lr;
                P[row * 64 + (((col >> 3) ^ (row & 7)) << 3) + (col & 7)] = (bf16_t)s[ct][r];
            }
        }
        bf16x8 ap0 = *(const bf16x8*)(P + lr * 64 + ((lk ^ (lr & 7)) << 3));
        bf16x8 ap1 = *(const bf16x8*)(P + lr * 64 + (((lk + 4) ^ (lr & 7)) << 3));
#pragma unroll
        for (int t = 0; t < 4; ++t) {
            int drow = t * 16 + lr;
            bf16x8 bv0 = *(const bf16x8*)(VtT + drow * 64 + ((lk ^ (drow & 7)) << 3));
            bf16x8 bv1 = *(const bf16x8*)(VtT + drow * 64 + (((lk + 4) ^ (drow & 7)) << 3));
            accO[t] = __builtin_amdgcn_mfma_f32_16x16x32_bf16(ap0, bv0, accO[t], 0, 0, 0);
            accO[t] = __builtin_amdgcn_mfma_f32_16x16x32_bf16(ap1, bv1, accO[t], 0, 0, 0);
        }
    }
    // epilogue: O / l -> AO[n, q, h*64 + d] bf16
#pragma unroll
    for (int r = 0; r < 4; ++r) {
        int q = q0 + lk * 4 + r;
        float inv = 1.0f / l[r];
        bf16_t* orow = AO + ((size_t)(n * SEQ + q)) * EMBED + h * HDIM;
#pragma unroll
        for (int t = 0; t < 4; ++t)
            orow[t * 16 + lr] = (bf16_t)(accO[t][r] * inv);
    }
}

// ---------------- Output projection: Out = Xa @ Wo^T + bo (f32 out) ----------------
__global__ __launch_bounds__(256) void outproj_kernel(const bf16_t* __restrict__ Xa,
                                                      const float* __restrict__ Wo,
                                                      const float* __restrict__ bo,
                                                      float* __restrict__ Out) {
    const int lane = threadIdx.x & 63;
    const int wv = threadIdx.x >> 6;
    const int lr = lane & 15, lk = lane >> 4;
    const int bc = blockIdx.x & 15;    // 16 col-blocks
    const int br = blockIdx.x >> 4;    // 128 row-blocks
    const int r0 = br * 64 + wv * 16;
    const int c0 = bc * 64;

    f32x4 acc[4] = {};
    const bf16_t* xrow = Xa + (size_t)(r0 + lr) * EMBED;
    for (int k0 = 0; k0 < EMBED; k0 += 32) {
        bf16x8 a = *(const bf16x8*)(xrow + k0 + lk * 8);
#pragma unroll
        for (int t = 0; t < 4; ++t) {
            const float* wrow = Wo + (size_t)(c0 + t * 16 + lr) * EMBED + k0;
            bf16x8 b = load_cvt8(wrow + lk * 8);
            acc[t] = __builtin_amdgcn_mfma_f32_16x16x32_bf16(a, b, acc[t], 0, 0, 0);
        }
    }
#pragma unroll
    for (int r = 0; r < 4; ++r) {
        int row = r0 + lk * 4 + r;
        float* orow = Out + (size_t)row * EMBED;
#pragma unroll
        for (int t = 0; t < 4; ++t) {
            int col = c0 + t * 16 + lr;
            orow[col] = acc[t][r] + bo[col];
        }
    }
}

extern "C" void kernel_launch(void* const* d_in, const int* in_sizes, int n_in,
                              void* d_out, int out_size, void* d_ws, size_t ws_size,
                              hipStream_t stream) {
    const float* values = (const float*)d_in[0];
    const float* keys   = (const float*)d_in[1];
    const float* query  = (const float*)d_in[2];
    const int*   mask   = (const int*)d_in[3];
    const float* Wv = (const float*)d_in[4];
    const float* Wk = (const float*)d_in[5];
    const float* Wq = (const float*)d_in[6];
    const float* Wo = (const float*)d_in[7];
    const float* bo = (const float*)d_in[8];
    float* out = (float*)d_out;

    char* ws = (char*)d_ws;
    const size_t SZ = (size_t)NB * HEADS * SEQ * HDIM * sizeof(bf16_t); // 16 MB
    bf16_t* Qp = (bf16_t*)(ws);
    bf16_t* Kp = (bf16_t*)(ws + SZ);
    bf16_t* Vp = (bf16_t*)(ws + 2 * SZ);
    bf16_t* Xa = (bf16_t*)(ws + 3 * SZ);

    dim3 blk(256);
    const int proj_grid = (NB * SEQ * HEADS) / 64;  // 2048
    proj_kernel<<<proj_grid, blk, 0, stream>>>(query, Wq, Qp);
    proj_kernel<<<proj_grid, blk, 0, stream>>>(keys, Wk, Kp);
    proj_kernel<<<proj_grid, blk, 0, stream>>>(values, Wv, Vp);

    const int attn_grid = (NB * HEADS) * (SEQ / QT);  // 2048
    attn_kernel<<<attn_grid, blk, 0, stream>>>(Qp, Kp, Vp, mask, Xa);

    const int op_grid = ((NB * SEQ) / 64) * (EMBED / 64);  // 2048
    outproj_kernel<<<op_grid, blk, 0, stream>>>(Xa, Wo, bo, out);
}

// Round 2
// 199.619 us; speedup vs baseline: 3.2295x; 3.2295x over previous
//
#include <hip/hip_runtime.h>
#include <hip/hip_bf16.h>

#define EMBED 1024
#define HEADS 16
#define HDIM 64
#define NB 4
#define SEQ 2048

typedef __bf16 bf16_t;
typedef bf16_t bf16x8 __attribute__((ext_vector_type(8)));
typedef float f32x4 __attribute__((ext_vector_type(4)));

static __device__ __forceinline__ bf16x8 cvt8(f32x4 a, f32x4 b) {
    bf16x8 r;
    r[0]=(bf16_t)a[0]; r[1]=(bf16_t)a[1]; r[2]=(bf16_t)a[2]; r[3]=(bf16_t)a[3];
    r[4]=(bf16_t)b[0]; r[5]=(bf16_t)b[1]; r[6]=(bf16_t)b[2]; r[7]=(bf16_t)b[3];
    return r;
}
static __device__ __forceinline__ bf16x8 load_cvt8(const float* __restrict__ p) {
    f32x4 a = *reinterpret_cast<const f32x4*>(p);
    f32x4 b = *reinterpret_cast<const f32x4*>(p + 4);
    return cvt8(a, b);
}

// ------------- Projection: Y[n,h,s,:] = (X[n,s,h*64:+64] @ W^T) * scale  (bf16) -------
__global__ __launch_bounds__(256) void proj_kernel(const float* __restrict__ X,
                                                   const float* __restrict__ W,
                                                   bf16_t* __restrict__ Y, float scale) {
    const int lane = threadIdx.x & 63;
    const int wv = threadIdx.x >> 6;
    const int lr = lane & 15;
    const int lk = lane >> 4;
    const int r0 = blockIdx.x * 64 + wv * 16;  // linear row = (n*SEQ+s)*HEADS + h

    const float* xrow = X + (size_t)(r0 + lr) * HDIM;
    bf16x8 a0 = load_cvt8(xrow + lk * 8);
    bf16x8 a1 = load_cvt8(xrow + 32 + lk * 8);

    f32x4 acc[4] = {};
#pragma unroll
    for (int t = 0; t < 4; ++t) {
        const float* wrow = W + (size_t)(t * 16 + lr) * HDIM;
        bf16x8 b0 = load_cvt8(wrow + lk * 8);
        bf16x8 b1 = load_cvt8(wrow + 32 + lk * 8);
        acc[t] = __builtin_amdgcn_mfma_f32_16x16x32_bf16(a0, b0, acc[t], 0, 0, 0);
        acc[t] = __builtin_amdgcn_mfma_f32_16x16x32_bf16(a1, b1, acc[t], 0, 0, 0);
    }
#pragma unroll
    for (int r = 0; r < 4; ++r) {
        int row = r0 + lk * 4 + r;
        int n = row / (SEQ * HEADS);
        int rem = row % (SEQ * HEADS);
        int s = rem / HEADS;
        int h = rem % HEADS;
        bf16_t* yrow = Y + ((size_t)(n * HEADS + h) * SEQ + s) * HDIM;
#pragma unroll
        for (int t = 0; t < 4; ++t)
            yrow[t * 16 + lr] = (bf16_t)(acc[t][r] * scale);
    }
}

// ------------- Flash attention, swapped QK^T, no-max softmax, dbuf staging -------------
#define KT 64
#define QPB 128
#define NT (SEQ / KT)

__global__ __launch_bounds__(256, 4) void attn_kernel(const bf16_t* __restrict__ Qp,
                                                      const bf16_t* __restrict__ Kp,
                                                      const bf16_t* __restrict__ Vp,
                                                      const int* __restrict__ mask,
                                                      bf16_t* __restrict__ AO) {
    __shared__ __align__(16) bf16_t Kt[2][64 * 64];
    __shared__ __align__(16) bf16_t Vt[2][64 * 64];

    const int tid = threadIdx.x;
    const int lane = tid & 63;
    const int w = tid >> 6;
    const int lr = lane & 15, g = lane >> 4;

    const int nh = blockIdx.x >> 4;   // (n*HEADS + h)
    const int qb = blockIdx.x & 15;
    const int n = nh >> 4, h = nh & 15;

    const bf16_t* Qh = Qp + (size_t)nh * SEQ * HDIM;
    const bf16_t* Kh = Kp + (size_t)nh * SEQ * HDIM;
    const bf16_t* Vh = Vp + (size_t)nh * SEQ * HDIM;
    const int* mrow = mask + n * SEQ;

    const int q0 = qb * QPB + w * 32;
    // Q B-fragments (pre-scaled by log2e/32 in projection)
    bf16x8 Qreg[2][2];
#pragma unroll
    for (int qt = 0; qt < 2; ++qt)
#pragma unroll
        for (int hf = 0; hf < 2; ++hf)
            Qreg[qt][hf] = *(const bf16x8*)(Qh + (size_t)(q0 + qt * 16 + lr) * HDIM + hf * 32 + g * 8);

    // staging index precompute
    int krow[2], kc[2], kwoff[2];
#pragma unroll
    for (int p = 0; p < 2; ++p) {
        int cid = tid + p * 256;
        krow[p] = cid >> 3; kc[p] = cid & 7;
        kwoff[p] = krow[p] * 64 + ((kc[p] ^ (krow[p] & 7)) << 3);
    }
    const int vkey = lane;
    const int vpos = 32 * (vkey >> 5) + 8 * ((vkey >> 2) & 3) + 4 * ((vkey >> 4) & 1) + (vkey & 3);

    float lacc[2] = {0.f, 0.f};
    f32x4 accO[2][4] = {};

    bf16x8 kst[2], vst[2];
#define LOADK(t) { _Pragma("unroll") for (int p = 0; p < 2; ++p) \
    kst[p] = *(const bf16x8*)(Kh + (size_t)((t) * 64 + krow[p]) * 64 + kc[p] * 8); }
#define LOADV(t) { _Pragma("unroll") for (int p = 0; p < 2; ++p) \
    vst[p] = *(const bf16x8*)(Vh + (size_t)((t) * 64 + vkey) * 64 + (w + p * 4) * 8); }
#define WRITEK(b) { _Pragma("unroll") for (int p = 0; p < 2; ++p) \
    *(bf16x8*)(Kt[b] + kwoff[p]) = kst[p]; }
#define WRITEV(b) { _Pragma("unroll") for (int p = 0; p < 2; ++p) { \
    _Pragma("unroll") for (int j = 0; j < 8; ++j) \
        Vt[b][((w + p * 4) * 8 + j) * 64 + (((vpos >> 3) ^ j) << 3) + (vpos & 7)] = vst[p][j]; } }

    LOADK(0); LOADV(0);
    WRITEK(0); WRITEV(0);

    for (int t = 0; t < NT; ++t) {
        const int cur = t & 1;
        __syncthreads();
        if (t + 1 < NT) { LOADK(t + 1); LOADV(t + 1); }

        int mv = mrow[t * 64 + lane];
        bool allone = __all(mv != 0);

        // QK^T (swapped: A=K rows, B=Q) fused with exp2 and P-fragment build
        bf16x8 paf[2][2];
        const bf16_t* Kb = Kt[cur];
#pragma unroll
        for (int ct = 0; ct < 4; ++ct) {
            int row = ct * 16 + lr;
            bf16x8 kf0 = *(const bf16x8*)(Kb + row * 64 + ((g ^ (row & 7)) << 3));
            bf16x8 kf1 = *(const bf16x8*)(Kb + row * 64 + (((4 + g) ^ (row & 7)) << 3));
#pragma unroll
            for (int qt = 0; qt < 2; ++qt) {
                f32x4 z = {};
                z = __builtin_amdgcn_mfma_f32_16x16x32_bf16(kf0, Qreg[qt][0], z, 0, 0, 0);
                z = __builtin_amdgcn_mfma_f32_16x16x32_bf16(kf1, Qreg[qt][1], z, 0, 0, 0);
                if (allone) {
#pragma unroll
                    for (int r = 0; r < 4; ++r) z[r] = __builtin_amdgcn_exp2f(z[r]);
                } else {
#pragma unroll
                    for (int r = 0; r < 4; ++r) {
                        int key = ct * 16 + g * 4 + r;
                        int mk = __shfl(mv, key);
                        z[r] = mk ? __builtin_amdgcn_exp2f(z[r]) : 0.f;
                    }
                }
                lacc[qt] += z[0] + z[1] + z[2] + z[3];
#pragma unroll
                for (int r = 0; r < 4; ++r)
                    paf[qt][ct >> 1][(ct & 1) * 4 + r] = (bf16_t)z[r];
            }
        }

        // PV: B-fragments from position-permuted V (keys match paf's k-order)
        const bf16_t* Vb = Vt[cur];
#pragma unroll
        for (int ctd = 0; ctd < 4; ++ctd) {
            int row = ctd * 16 + lr;  // d
            bf16x8 vf0 = *(const bf16x8*)(Vb + row * 64 + ((g ^ (row & 7)) << 3));
            bf16x8 vf1 = *(const bf16x8*)(Vb + row * 64 + (((4 + g) ^ (row & 7)) << 3));
#pragma unroll
            for (int qt = 0; qt < 2; ++qt) {
                accO[qt][ctd] = __builtin_amdgcn_mfma_f32_16x16x32_bf16(paf[qt][0], vf0, accO[qt][ctd], 0, 0, 0);
                accO[qt][ctd] = __builtin_amdgcn_mfma_f32_16x16x32_bf16(paf[qt][1], vf1, accO[qt][ctd], 0, 0, 0);
            }
        }
        if (t + 1 < NT) { WRITEK(cur ^ 1); WRITEV(cur ^ 1); }
    }

    // final denominator reduce + write
#pragma unroll
    for (int qt = 0; qt < 2; ++qt) {
        float v = lacc[qt];
        v += __shfl_xor(v, 16);
        v += __shfl_xor(v, 32);
        lacc[qt] = v;
    }
#pragma unroll
    for (int qt = 0; qt < 2; ++qt)
#pragma unroll
        for (int r = 0; r < 4; ++r) {
            float denom = __shfl(lacc[qt], g * 4 + r);
            float inv = 1.0f / denom;
            int q = q0 + qt * 16 + g * 4 + r;
            bf16_t* orow = AO + ((size_t)(n * SEQ + q)) * EMBED + h * HDIM;
#pragma unroll
            for (int ctd = 0; ctd < 4; ++ctd)
                orow[ctd * 16 + lr] = (bf16_t)(accO[qt][ctd][r] * inv);
        }
#undef LOADK
#undef LOADV
#undef WRITEK
#undef WRITEV
}

// ------------- Output projection: 128x128-tile dbuf GEMM, Out = Xa @ Wo^T + bo --------
__global__ __launch_bounds__(256, 2) void outproj_kernel(const bf16_t* __restrict__ Xa,
                                                         const float* __restrict__ Wo,
                                                         const float* __restrict__ bo,
                                                         float* __restrict__ Out) {
    __shared__ __align__(16) bf16_t As[2][128 * 64];
    __shared__ __align__(16) bf16_t Bs[2][128 * 64];
    const int tid = threadIdx.x;
    const int lane = tid & 63, w = tid >> 6;
    const int lr = lane & 15, g = lane >> 4;
    const int wm = w >> 1, wn = w & 1;
    const int bm = blockIdx.x >> 3, bn = blockIdx.x & 7;
    const int r0 = bm * 128, c0 = bn * 128;

    int srow[4], sc[4], soff[4];
#pragma unroll
    for (int p = 0; p < 4; ++p) {
        int cid = tid + p * 256;
        srow[p] = cid >> 3; sc[p] = cid & 7;
        soff[p] = srow[p] * 64 + ((sc[p] ^ (srow[p] & 7)) << 3);
    }

    f32x4 acc[4][4] = {};
    bf16x8 ast[4];
    f32x4 bstf[4][2];

#define LOADA(s) { _Pragma("unroll") for (int p = 0; p < 4; ++p) \
    ast[p] = *(const bf16x8*)(Xa + (size_t)(r0 + srow[p]) * EMBED + (s) * 64 + sc[p] * 8); }
#define LOADB(s) { _Pragma("unroll") for (int p = 0; p < 4; ++p) { \
    const float* wp = Wo + (size_t)(c0 + srow[p]) * EMBED + (s) * 64 + sc[p] * 8; \
    bstf[p][0] = *reinterpret_cast<const f32x4*>(wp); \
    bstf[p][1] = *reinterpret_cast<const f32x4*>(wp + 4); } }
#define WRITEA(b) { _Pragma("unroll") for (int p = 0; p < 4; ++p) \
    *(bf16x8*)(As[b] + soff[p]) = ast[p]; }
#define WRITEB(b) { _Pragma("unroll") for (int p = 0; p < 4; ++p) \
    *(bf16x8*)(Bs[b] + soff[p]) = cvt8(bstf[p][0], bstf[p][1]); }

    LOADA(0); LOADB(0);
    WRITEA(0); WRITEB(0);

    for (int ks = 0; ks < 16; ++ks) {
        const int cur = ks & 1;
        __syncthreads();
        if (ks + 1 < 16) { LOADA(ks + 1); LOADB(ks + 1); }
        const bf16_t* Ab = As[cur];
        const bf16_t* Bb = Bs[cur];
#pragma unroll
        for (int hf = 0; hf < 2; ++hf) {
            bf16x8 af[4], bfr[4];
#pragma unroll
            for (int i = 0; i < 4; ++i) {
                int ar = wm * 64 + i * 16 + lr;
                af[i] = *(const bf16x8*)(Ab + ar * 64 + (((hf * 4 + g) ^ (ar & 7)) << 3));
                int br = wn * 64 + i * 16 + lr;
                bfr[i] = *(const bf16x8*)(Bb + br * 64 + (((hf * 4 + g) ^ (br & 7)) << 3));
            }
#pragma unroll
            for (int i = 0; i < 4; ++i)
#pragma unroll
                for (int j = 0; j < 4; ++j)
                    acc[i][j] = __builtin_amdgcn_mfma_f32_16x16x32_bf16(af[i], bfr[j], acc[i][j], 0, 0, 0);
        }
        if (ks + 1 < 16) { WRITEA(cur ^ 1); WRITEB(cur ^ 1); }
    }
#pragma unroll
    for (int i = 0; i < 4; ++i)
#pragma unroll
        for (int r = 0; r < 4; ++r) {
            int row = r0 + wm * 64 + i * 16 + g * 4 + r;
            float* orow = Out + (size_t)row * EMBED;
#pragma unroll
            for (int j = 0; j < 4; ++j) {
                int col = c0 + wn * 64 + j * 16 + lr;
                orow[col] = acc[i][j][r] + bo[col];
            }
        }
#undef LOADA
#undef LOADB
#undef WRITEA
#undef WRITEB
}

extern "C" void kernel_launch(void* const* d_in, const int* in_sizes, int n_in,
                              void* d_out, int out_size, void* d_ws, size_t ws_size,
                              hipStream_t stream) {
    const float* values = (const float*)d_in[0];
    const float* keys   = (const float*)d_in[1];
    const float* query  = (const float*)d_in[2];
    const int*   mask   = (const int*)d_in[3];
    const float* Wv = (const float*)d_in[4];
    const float* Wk = (const float*)d_in[5];
    const float* Wq = (const float*)d_in[6];
    const float* Wo = (const float*)d_in[7];
    const float* bo = (const float*)d_in[8];
    float* out = (float*)d_out;

    char* ws = (char*)d_ws;
    const size_t SZ = (size_t)NB * HEADS * SEQ * HDIM * sizeof(bf16_t);  // 16 MB
    bf16_t* Qp = (bf16_t*)(ws);
    bf16_t* Kp = (bf16_t*)(ws + SZ);
    bf16_t* Vp = (bf16_t*)(ws + 2 * SZ);
    bf16_t* Xa = (bf16_t*)(ws + 3 * SZ);

    dim3 blk(256);
    const int proj_grid = (NB * SEQ * HEADS) / 64;  // 2048
    const float qscale = 0.0450842200278f;          // log2(e) / sqrt(1024)
    proj_kernel<<<proj_grid, blk, 0, stream>>>(query, Wq, Qp, qscale);
    proj_kernel<<<proj_grid, blk, 0, stream>>>(keys, Wk, Kp, 1.0f);
    proj_kernel<<<proj_grid, blk, 0, stream>>>(values, Wv, Vp, 1.0f);

    const int attn_grid = (NB * HEADS) * (SEQ / QPB);  // 1024
    attn_kernel<<<attn_grid, blk, 0, stream>>>(Qp, Kp, Vp, mask, Xa);

    const int op_grid = ((NB * SEQ) / 128) * (EMBED / 128);  // 512
    outproj_kernel<<<op_grid, blk, 0, stream>>>(Xa, Wo, bo, out);
}

// Round 3
// 179.307 us; speedup vs baseline: 3.5953x; 1.1133x over previous
//
#include <hip/hip_runtime.h>
#include <hip/hip_bf16.h>

#define EMBED 1024
#define HEADS 16
#define HDIM 64
#define NB 4
#define SEQ 2048

typedef __bf16 bf16_t;
typedef bf16_t bf16x4 __attribute__((ext_vector_type(4)));
typedef bf16_t bf16x8 __attribute__((ext_vector_type(8)));
typedef float f32x4 __attribute__((ext_vector_type(4)));

static __device__ __forceinline__ bf16x8 cvt8(f32x4 a, f32x4 b) {
    bf16x8 r;
    r[0]=(bf16_t)a[0]; r[1]=(bf16_t)a[1]; r[2]=(bf16_t)a[2]; r[3]=(bf16_t)a[3];
    r[4]=(bf16_t)b[0]; r[5]=(bf16_t)b[1]; r[6]=(bf16_t)b[2]; r[7]=(bf16_t)b[3];
    return r;
}
static __device__ __forceinline__ bf16x8 load_cvt8(const float* __restrict__ p) {
    f32x4 a = *reinterpret_cast<const f32x4*>(p);
    f32x4 b = *reinterpret_cast<const f32x4*>(p + 4);
    return cvt8(a, b);
}

// ------------- Projection (Q,K): Y[n,h,s,:] = (X[n,s,h*64:+64] @ W^T) * scale -------
__global__ __launch_bounds__(256) void proj_kernel(const float* __restrict__ X,
                                                   const float* __restrict__ W,
                                                   bf16_t* __restrict__ Y, float scale) {
    const int lane = threadIdx.x & 63;
    const int wv = threadIdx.x >> 6;
    const int lr = lane & 15;
    const int lk = lane >> 4;
    const int r0 = blockIdx.x * 64 + wv * 16;  // linear row = (n*SEQ+s)*HEADS + h

    const float* xrow = X + (size_t)(r0 + lr) * HDIM;
    bf16x8 a0 = load_cvt8(xrow + lk * 8);
    bf16x8 a1 = load_cvt8(xrow + 32 + lk * 8);

    f32x4 acc[4] = {};
#pragma unroll
    for (int t = 0; t < 4; ++t) {
        const float* wrow = W + (size_t)(t * 16 + lr) * HDIM;
        bf16x8 b0 = load_cvt8(wrow + lk * 8);
        bf16x8 b1 = load_cvt8(wrow + 32 + lk * 8);
        acc[t] = __builtin_amdgcn_mfma_f32_16x16x32_bf16(a0, b0, acc[t], 0, 0, 0);
        acc[t] = __builtin_amdgcn_mfma_f32_16x16x32_bf16(a1, b1, acc[t], 0, 0, 0);
    }
#pragma unroll
    for (int r = 0; r < 4; ++r) {
        int row = r0 + lk * 4 + r;
        int n = row / (SEQ * HEADS);
        int rem = row % (SEQ * HEADS);
        int s = rem / HEADS;
        int h = rem % HEADS;
        bf16_t* yrow = Y + ((size_t)(n * HEADS + h) * SEQ + s) * HDIM;
#pragma unroll
        for (int t = 0; t < 4; ++t)
            yrow[t * 16 + lr] = (bf16_t)(acc[t][r] * scale);
    }
}

// ------------- V^T projection: Vt[n,h,d,s] = Wv @ X^T  (bf16) -------------
// C = A*B with A = Wv rows (d x dx), B = X rows as B-frags (dx x s).
__global__ __launch_bounds__(256) void vproj_kernel(const float* __restrict__ X,
                                                    const float* __restrict__ Wv,
                                                    bf16_t* __restrict__ Vt_g) {
    const int lane = threadIdx.x & 63;
    const int w = threadIdx.x >> 6;
    const int lr = lane & 15, g = lane >> 4;
    const int nh = blockIdx.x >> 5;     // 64
    const int sc = blockIdx.x & 31;     // 32 s-chunks of 64
    const int n = nh >> 4, h = nh & 15;
    const int s0 = sc * 64 + w * 16;    // this wave's 16 s-columns

    // B-frags: B[k=dx][col=s] -> lane reads X[s0+lr][h*64 + half*32 + g*8 ..+8]
    const float* xrow = X + ((size_t)(n * SEQ) + s0 + lr) * EMBED + h * HDIM;
    bf16x8 bx0 = load_cvt8(xrow + g * 8);
    bf16x8 bx1 = load_cvt8(xrow + 32 + g * 8);

    f32x4 acc[4] = {};
#pragma unroll
    for (int dt = 0; dt < 4; ++dt) {
        const float* wrow = Wv + (size_t)(dt * 16 + lr) * HDIM;
        bf16x8 wa0 = load_cvt8(wrow + g * 8);
        bf16x8 wa1 = load_cvt8(wrow + 32 + g * 8);
        acc[dt] = __builtin_amdgcn_mfma_f32_16x16x32_bf16(wa0, bx0, acc[dt], 0, 0, 0);
        acc[dt] = __builtin_amdgcn_mfma_f32_16x16x32_bf16(wa1, bx1, acc[dt], 0, 0, 0);
    }
    // C[row=d][col=s]: d = dt*16 + g*4 + r, s = s0 + lr
#pragma unroll
    for (int dt = 0; dt < 4; ++dt)
#pragma unroll
        for (int r = 0; r < 4; ++r)
            Vt_g[((size_t)nh * HDIM + dt * 16 + g * 4 + r) * SEQ + s0 + lr] = (bf16_t)acc[dt][r];
}

// ------------- Flash attention: 4 waves x 64q, KT=64, V^T staged, dbuf -------------
#define KT 64
#define QPW 64
#define QPB 256
#define NT (SEQ / KT)

__global__ __launch_bounds__(256, 2) void attn_kernel(const bf16_t* __restrict__ Qp,
                                                      const bf16_t* __restrict__ Kp,
                                                      const bf16_t* __restrict__ Vt_g,
                                                      const int* __restrict__ mask,
                                                      bf16_t* __restrict__ AO) {
    __shared__ __align__(16) bf16_t Kt[2][64 * 64];
    __shared__ __align__(16) bf16_t Vt[2][64 * 64];

    const int tid = threadIdx.x;
    const int lane = tid & 63;
    const int w = tid >> 6;
    const int lr = lane & 15, g = lane >> 4;

    const int nh = blockIdx.x & 63;   // XCD = bid%8 = nh%8 -> all qb of an nh share an XCD
    const int qb = blockIdx.x >> 6;
    const int n = nh >> 4, h = nh & 15;

    const bf16_t* Qh = Qp + (size_t)nh * SEQ * HDIM;
    const bf16_t* Kh = Kp + (size_t)nh * SEQ * HDIM;
    const bf16_t* Vh = Vt_g + (size_t)nh * HDIM * SEQ;   // [d][s]
    const int* mrow = mask + n * SEQ;

    const int q0 = qb * QPB + w * QPW;
    bf16x8 Qreg[4][2];
#pragma unroll
    for (int qt = 0; qt < 4; ++qt)
#pragma unroll
        for (int hf = 0; hf < 2; ++hf)
            Qreg[qt][hf] = *(const bf16x8*)(Qh + (size_t)(q0 + qt * 16 + lr) * HDIM + hf * 32 + g * 8);

    int krow[2], kc[2], kwoff[2];
#pragma unroll
    for (int p = 0; p < 2; ++p) {
        int cid = tid + p * 256;
        krow[p] = cid >> 3; kc[p] = cid & 7;
        kwoff[p] = krow[p] * 64 + ((kc[p] ^ (krow[p] & 7)) << 3);
    }

    float lacc[4] = {};
    f32x4 accO[4][4] = {};

    bf16x8 kst[2], vst[2];
#define LOADK(t) { _Pragma("unroll") for (int p = 0; p < 2; ++p) \
    kst[p] = *(const bf16x8*)(Kh + (size_t)((t) * 64 + krow[p]) * 64 + kc[p] * 8); }
#define LOADV(t) { _Pragma("unroll") for (int p = 0; p < 2; ++p) \
    vst[p] = *(const bf16x8*)(Vh + (size_t)krow[p] * SEQ + (t) * 64 + kc[p] * 8); }
#define WRITEK(b) { _Pragma("unroll") for (int p = 0; p < 2; ++p) \
    *(bf16x8*)(Kt[b] + kwoff[p]) = kst[p]; }
#define WRITEV(b) { _Pragma("unroll") for (int p = 0; p < 2; ++p) \
    *(bf16x8*)(Vt[b] + kwoff[p]) = vst[p]; }

    LOADK(0); LOADV(0);
    WRITEK(0); WRITEV(0);

    for (int t = 0; t < NT; ++t) {
        const int cur = t & 1;
        __syncthreads();
        if (t + 1 < NT) { LOADK(t + 1); LOADV(t + 1); }

        int mv = mrow[t * 64 + lane];
        bool allone = __all(mv != 0);

        // QK^T (swapped: A=K rows, B=Q) fused with exp2 and P-fragment build
        bf16x8 paf[4][2];
        const bf16_t* Kb = Kt[cur];
#pragma unroll
        for (int ct = 0; ct < 4; ++ct) {
            int row = ct * 16 + lr;
            bf16x8 kf0 = *(const bf16x8*)(Kb + row * 64 + ((g ^ (row & 7)) << 3));
            bf16x8 kf1 = *(const bf16x8*)(Kb + row * 64 + (((4 + g) ^ (row & 7)) << 3));
#pragma unroll
            for (int qt = 0; qt < 4; ++qt) {
                f32x4 z = {};
                z = __builtin_amdgcn_mfma_f32_16x16x32_bf16(kf0, Qreg[qt][0], z, 0, 0, 0);
                z = __builtin_amdgcn_mfma_f32_16x16x32_bf16(kf1, Qreg[qt][1], z, 0, 0, 0);
                if (allone) {
#pragma unroll
                    for (int r = 0; r < 4; ++r) z[r] = __builtin_amdgcn_exp2f(z[r]);
                } else {
#pragma unroll
                    for (int r = 0; r < 4; ++r) {
                        int key = ct * 16 + g * 4 + r;
                        int mk = __shfl(mv, key);
                        z[r] = mk ? __builtin_amdgcn_exp2f(z[r]) : 0.f;
                    }
                }
                lacc[qt] += z[0] + z[1] + z[2] + z[3];
#pragma unroll
                for (int r = 0; r < 4; ++r)
                    paf[qt][ct >> 1][(ct & 1) * 4 + r] = (bf16_t)z[r];
            }
        }

        // PV from V^T tile [d][key]: lane reads row d = ctd*16+lr at key chunks
        const bf16_t* Vb = Vt[cur];
        __builtin_amdgcn_s_setprio(1);
#pragma unroll
        for (int ctd = 0; ctd < 4; ++ctd) {
            int row = ctd * 16 + lr;
            int rs = row & 7;
            const bf16_t* vrow = Vb + row * 64;
            bf16x4 e0 = *(const bf16x4*)(vrow + ((((g >> 1) + 0) ^ rs) << 3) + (g & 1) * 4);
            bf16x4 e1 = *(const bf16x4*)(vrow + ((((g >> 1) + 2) ^ rs) << 3) + (g & 1) * 4);
            bf16x4 e2 = *(const bf16x4*)(vrow + ((((g >> 1) + 4) ^ rs) << 3) + (g & 1) * 4);
            bf16x4 e3 = *(const bf16x4*)(vrow + ((((g >> 1) + 6) ^ rs) << 3) + (g & 1) * 4);
            bf16x8 vf0, vf1;
#pragma unroll
            for (int j = 0; j < 4; ++j) {
                vf0[j] = e0[j]; vf0[4 + j] = e1[j];
                vf1[j] = e2[j]; vf1[4 + j] = e3[j];
            }
#pragma unroll
            for (int qt = 0; qt < 4; ++qt) {
                accO[qt][ctd] = __builtin_amdgcn_mfma_f32_16x16x32_bf16(paf[qt][0], vf0, accO[qt][ctd], 0, 0, 0);
                accO[qt][ctd] = __builtin_amdgcn_mfma_f32_16x16x32_bf16(paf[qt][1], vf1, accO[qt][ctd], 0, 0, 0);
            }
        }
        __builtin_amdgcn_s_setprio(0);
        if (t + 1 < NT) { WRITEK(cur ^ 1); WRITEV(cur ^ 1); }
    }

    // final denominator reduce + write
#pragma unroll
    for (int qt = 0; qt < 4; ++qt) {
        float v = lacc[qt];
        v += __shfl_xor(v, 16);
        v += __shfl_xor(v, 32);
        lacc[qt] = v;
    }
#pragma unroll
    for (int qt = 0; qt < 4; ++qt)
#pragma unroll
        for (int r = 0; r < 4; ++r) {
            float denom = __shfl(lacc[qt], g * 4 + r);
            float inv = 1.0f / denom;
            int q = q0 + qt * 16 + g * 4 + r;
            bf16_t* orow = AO + ((size_t)(n * SEQ + q)) * EMBED + h * HDIM;
#pragma unroll
            for (int ctd = 0; ctd < 4; ++ctd)
                orow[ctd * 16 + lr] = (bf16_t)(accO[qt][ctd][r] * inv);
        }
#undef LOADK
#undef LOADV
#undef WRITEK
#undef WRITEV
}

// ------------- Output projection: 128x128-tile dbuf GEMM, Out = Xa @ Wo^T + bo --------
__global__ __launch_bounds__(256, 2) void outproj_kernel(const bf16_t* __restrict__ Xa,
                                                         const float* __restrict__ Wo,
                                                         const float* __restrict__ bo,
                                                         float* __restrict__ Out) {
    __shared__ __align__(16) bf16_t As[2][128 * 64];
    __shared__ __align__(16) bf16_t Bs[2][128 * 64];
    const int tid = threadIdx.x;
    const int lane = tid & 63, w = tid >> 6;
    const int lr = lane & 15, g = lane >> 4;
    const int wm = w >> 1, wn = w & 1;
    const int bm = blockIdx.x >> 3, bn = blockIdx.x & 7;
    const int r0 = bm * 128, c0 = bn * 128;

    int srow[4], sc[4], soff[4];
#pragma unroll
    for (int p = 0; p < 4; ++p) {
        int cid = tid + p * 256;
        srow[p] = cid >> 3; sc[p] = cid & 7;
        soff[p] = srow[p] * 64 + ((sc[p] ^ (srow[p] & 7)) << 3);
    }

    f32x4 acc[4][4] = {};
    bf16x8 ast[4];
    f32x4 bstf[4][2];

#define LOADA(s) { _Pragma("unroll") for (int p = 0; p < 4; ++p) \
    ast[p] = *(const bf16x8*)(Xa + (size_t)(r0 + srow[p]) * EMBED + (s) * 64 + sc[p] * 8); }
#define LOADB(s) { _Pragma("unroll") for (int p = 0; p < 4; ++p) { \
    const float* wp = Wo + (size_t)(c0 + srow[p]) * EMBED + (s) * 64 + sc[p] * 8; \
    bstf[p][0] = *reinterpret_cast<const f32x4*>(wp); \
    bstf[p][1] = *reinterpret_cast<const f32x4*>(wp + 4); } }
#define WRITEA(b) { _Pragma("unroll") for (int p = 0; p < 4; ++p) \
    *(bf16x8*)(As[b] + soff[p]) = ast[p]; }
#define WRITEB(b) { _Pragma("unroll") for (int p = 0; p < 4; ++p) \
    *(bf16x8*)(Bs[b] + soff[p]) = cvt8(bstf[p][0], bstf[p][1]); }

    LOADA(0); LOADB(0);
    WRITEA(0); WRITEB(0);

    for (int ks = 0; ks < 16; ++ks) {
        const int cur = ks & 1;
        __syncthreads();
        if (ks + 1 < 16) { LOADA(ks + 1); LOADB(ks + 1); }
        const bf16_t* Ab = As[cur];
        const bf16_t* Bb = Bs[cur];
#pragma unroll
        for (int hf = 0; hf < 2; ++hf) {
            bf16x8 af[4], bfr[4];
#pragma unroll
            for (int i = 0; i < 4; ++i) {
                int ar = wm * 64 + i * 16 + lr;
                af[i] = *(const bf16x8*)(Ab + ar * 64 + (((hf * 4 + g) ^ (ar & 7)) << 3));
                int br = wn * 64 + i * 16 + lr;
                bfr[i] = *(const bf16x8*)(Bb + br * 64 + (((hf * 4 + g) ^ (br & 7)) << 3));
            }
#pragma unroll
            for (int i = 0; i < 4; ++i)
#pragma unroll
                for (int j = 0; j < 4; ++j)
                    acc[i][j] = __builtin_amdgcn_mfma_f32_16x16x32_bf16(af[i], bfr[j], acc[i][j], 0, 0, 0);
        }
        if (ks + 1 < 16) { WRITEA(cur ^ 1); WRITEB(cur ^ 1); }
    }
#pragma unroll
    for (int i = 0; i < 4; ++i)
#pragma unroll
        for (int r = 0; r < 4; ++r) {
            int row = r0 + wm * 64 + i * 16 + g * 4 + r;
            float* orow = Out + (size_t)row * EMBED;
#pragma unroll
            for (int j = 0; j < 4; ++j) {
                int col = c0 + wn * 64 + j * 16 + lr;
                orow[col] = acc[i][j][r] + bo[col];
            }
        }
#undef LOADA
#undef LOADB
#undef WRITEA
#undef WRITEB
}

extern "C" void kernel_launch(void* const* d_in, const int* in_sizes, int n_in,
                              void* d_out, int out_size, void* d_ws, size_t ws_size,
                              hipStream_t stream) {
    const float* values = (const float*)d_in[0];
    const float* keys   = (const float*)d_in[1];
    const float* query  = (const float*)d_in[2];
    const int*   mask   = (const int*)d_in[3];
    const float* Wv = (const float*)d_in[4];
    const float* Wk = (const float*)d_in[5];
    const float* Wq = (const float*)d_in[6];
    const float* Wo = (const float*)d_in[7];
    const float* bo = (const float*)d_in[8];
    float* out = (float*)d_out;

    char* ws = (char*)d_ws;
    const size_t SZ = (size_t)NB * HEADS * SEQ * HDIM * sizeof(bf16_t);  // 16 MB
    bf16_t* Qp = (bf16_t*)(ws);
    bf16_t* Kp = (bf16_t*)(ws + SZ);
    bf16_t* Vt = (bf16_t*)(ws + 2 * SZ);   // [n,h,d,s]
    bf16_t* Xa = (bf16_t*)(ws + 3 * SZ);

    dim3 blk(256);
    const int proj_grid = (NB * SEQ * HEADS) / 64;  // 2048
    const float qscale = 0.0450842200278f;          // log2(e) / sqrt(1024)
    proj_kernel<<<proj_grid, blk, 0, stream>>>(query, Wq, Qp, qscale);
    proj_kernel<<<proj_grid, blk, 0, stream>>>(keys, Wk, Kp, 1.0f);
    vproj_kernel<<<NB * HEADS * (SEQ / 64), blk, 0, stream>>>(values, Wv, Vt);  // 2048

    const int attn_grid = (NB * HEADS) * (SEQ / QPB);  // 512
    attn_kernel<<<attn_grid, blk, 0, stream>>>(Qp, Kp, Vt, mask, Xa);

    const int op_grid = ((NB * SEQ) / 128) * (EMBED / 128);  // 512
    outproj_kernel<<<op_grid, blk, 0, stream>>>(Xa, Wo, bo, out);
}